// Round 6
// baseline (96.809 us; speedup 1.0000x reference)
//
#include <hip/hip_runtime.h>
#include <stdint.h>

#define S 9          // PW*PW
#define LSZ 64       // GRID*GRID sites
#define NP 64        // plaquettes
#define M 128
#define BATCH 2048

#define NCH  8               // batch chunks
#define CHB  (BATCH / NCH)   // 256 batches per chunk
#define NBLK (NP * NCH)      // 512 blocks: block = (p, chunk)
#define NTHR 256
#define BPWV (CHB / 4)       // 64 batches per wave

// Monotonic per-chunk tickets in .bss (zeroed at load, never reset; wrap-safe
// since 2^32 % 64 == 0). The 64th finisher of a chunk owns the tail reduce.
__device__ unsigned g_tk[NCH];

// ---------------------------------------------------------------------------
// One dispatch, ZERO waiting (R5 post-mortem: every wait-for-everyone
// primitive costs 10-50us on 8 XCDs; so remove the dependency, not the cost).
//
// Block (p, bc):
//   1. build As[32][M] (pattern bits 0..4) / Bs[16][M] (bits 5..8) for its
//      single plaquette p (one 9.2KB eps gather, 8x total redundancy).
//   2. eval its 256 batches: ballot -> wave-uniform 9-bit pattern via
//      bit-math (scalar!), As[lo][l]*Bs[hi][l] + As[lo][l+64]*Bs[hi][l+64],
//      64-lane shfl tree -> pstage.
//   3. one coalesced agent-scope (write-through) store of 256 partials,
//      vmcnt drained by __syncthreads (R5-proven visibility recipe),
//      one relaxed atomicAdd on the chunk ticket, then EXIT (no spin).
//   4. the 64th finisher alone sums partial[p][b] over p ascending
//      (deterministic) and writes out[b] for its 256 batches.
// ---------------------------------------------------------------------------
__global__ __launch_bounds__(NTHR, 2) void fused(
    const int*   __restrict__ inputs,  // [BATCH][LSZ]
    const int*   __restrict__ plq,     // [NP][S]  (unused: regular geometry)
    const float* __restrict__ eps,     // [2][NP][M][S]
    float*       __restrict__ partial, // [NP][BATCH]  (ws, 512 KB)
    float*       __restrict__ out)     // [BATCH]
{
    __shared__ float As[32][M + 4];
    __shared__ float Bs[16][M + 4];
    __shared__ float pstage[CHB];
    __shared__ int   lastflag;

    const int t  = threadIdx.x;
    const int w  = t >> 6;
    const int l  = t & 63;
    const int p  = blockIdx.x >> 3;     // 0..63
    const int bc = blockIdx.x & 7;      // 0..7
    const int b0 = bc * CHB;

    // ---------------- build As/Bs for plaquette p ----------------
    {
        const int m    = t & 127;
        const int half = t >> 7;        // As: bit4 split; Bs: bit8 split
        const float* ep = eps + (size_t)p * (M * S) + (size_t)m * S;
        const int dstride = NP * M * S; // 73728

        float e0[S], e1[S];
#pragma unroll
        for (int s = 0; s < S; ++s) {
            e0[s] = ep[s];
            e1[s] = ep[dstride + s];
        }
        float c01[4], b56[4];
#pragma unroll
        for (int i = 0; i < 4; ++i) {
            c01[i] = ((i & 1) ? e1[0] : e0[0]) * ((i & 2) ? e1[1] : e0[1]);
            b56[i] = ((i & 1) ? e1[5] : e0[5]) * ((i & 2) ? e1[6] : e0[6]);
        }
        // As rows: half 0 -> lo 0..15 (bit4=0), half 1 -> lo 16..31
        const float e4v = half ? e1[4] : e0[4];
        float c234[4];
#pragma unroll
        for (int j = 0; j < 4; ++j)
            c234[j] = ((j & 1) ? e1[2] : e0[2]) *
                      ((j & 2) ? e1[3] : e0[3]) * e4v;
        const int lob = half * 16;
#pragma unroll
        for (int k = 0; k < 16; ++k)
            As[lob + k][m] = c01[k & 3] * c234[k >> 2];
        // Bs rows: half 0 -> hi 0..7 (bit8=0), half 1 -> hi 8..15
        const float e8v = half ? e1[8] : e0[8];
        const float b78_0 = e0[7] * e8v;
        const float b78_1 = e1[7] * e8v;
        const int hib = half * 8;
#pragma unroll
        for (int k = 0; k < 8; ++k)
            Bs[hib + k][m] = b56[k & 3] * ((k & 4) ? b78_1 : b78_0);
    }
    __syncthreads();

    // ---------------- eval 64 batches per wave, single p ----------------
    const int pi = p >> 3;
    const int pj = p & 7;
#pragma unroll 4
    for (int i = 0; i < BPWV; ++i) {
        const int bl = w * BPWV + i;                 // 0..255 within chunk
        const int v = inputs[(size_t)(b0 + bl) * LSZ + l];
        const unsigned long long mask = __ballot(v != 0);
        int pat = 0;                                 // wave-uniform (scalar)
#pragma unroll
        for (int di = 0; di < 3; ++di) {
            const int r = (pi + di) & 7;
            const unsigned row = (unsigned)(mask >> (8 * r)) & 0xFFu;
            pat |= (int)(((row | (row << 8)) >> pj) & 7u) << (3 * di);
        }
        const int lo = pat & 31;
        const int hi = pat >> 5;
        float acc = As[lo][l] * Bs[hi][l] + As[lo][l + 64] * Bs[hi][l + 64];
#pragma unroll
        for (int off = 32; off > 0; off >>= 1)
            acc += __shfl_down(acc, off, 64);
        if (l == 0) pstage[bl] = acc;
    }
    __syncthreads();

    // coalesced write-through partial store (R5-proven visibility recipe)
    __hip_atomic_store(&partial[(size_t)p * BATCH + b0 + t], pstage[t],
                       __ATOMIC_RELAXED, __HIP_MEMORY_SCOPE_AGENT);
    __syncthreads();   // vmcnt(0) drain: stores complete before the ticket

    if (t == 0) {
        const unsigned old =
            __hip_atomic_fetch_add(&g_tk[bc], 1u, __ATOMIC_RELAXED,
                                   __HIP_MEMORY_SCOPE_AGENT);
        lastflag = ((old & 63u) == 63u);
    }
    __syncthreads();
    if (!lastflag) return;               // everyone but the 64th exits: no spin

    // ---------------- tail: sum over p (fixed ascending order) ----------------
    const float* pr = partial + b0 + t;  // lines first-touched here: fresh
    float s = 0.f;
#pragma unroll
    for (int pp = 0; pp < NP; pp += 8) {
        float v0 = pr[(size_t)(pp + 0) * BATCH];
        float v1 = pr[(size_t)(pp + 1) * BATCH];
        float v2 = pr[(size_t)(pp + 2) * BATCH];
        float v3 = pr[(size_t)(pp + 3) * BATCH];
        float v4 = pr[(size_t)(pp + 4) * BATCH];
        float v5 = pr[(size_t)(pp + 5) * BATCH];
        float v6 = pr[(size_t)(pp + 6) * BATCH];
        float v7 = pr[(size_t)(pp + 7) * BATCH];
        s += v0; s += v1; s += v2; s += v3;
        s += v4; s += v5; s += v6; s += v7;
    }
    out[b0 + t] = s;
}

extern "C" void kernel_launch(void* const* d_in, const int* in_sizes, int n_in,
                              void* d_out, int out_size, void* d_ws, size_t ws_size,
                              hipStream_t stream) {
    const int*   inputs = (const int*)d_in[0];    // (BATCH, L) int32
    const int*   plq    = (const int*)d_in[1];    // (NP, 9) int32
    const float* eps    = (const float*)d_in[2];  // (2, NP, M, 9) fp32
    float* out = (float*)d_out;                   // (BATCH,) fp32
    float* partial = (float*)d_ws;                // NP*BATCH floats = 512 KB

    fused<<<NBLK, NTHR, 0, stream>>>(inputs, plq, eps, partial, out);
}

// Round 7
// 72.795 us; speedup vs baseline: 1.3299x; 1.3299x over previous
//
#include <hip/hip_runtime.h>
#include <stdint.h>

#define S 9          // PW*PW
#define LSZ 64       // GRID*GRID sites
#define NP 64        // plaquettes
#define M 128
#define BATCH 2048
#define MS (M * S)   // 1152 floats per (d,p) slice

#define PG   8               // plaquette groups (8 p each)
#define PGRP 8               // plaquettes per group
#define BC   64              // batch chunks
#define BPB  32              // batches per block
#define BPW  8               // batches per wave
#define NTHR 256
#define NBLK (PG * BC)       // 512 blocks
#define RAWN (2 * MS)        // 2304 dwords: both d-slices of one p

// Monotonic per-chunk tickets in .bss (zeroed at load, never reset;
// wrap-safe: 2^32 % 8 == 0). The 8th finisher of a chunk does the tail.
__device__ unsigned g_tk[BC];

// ---------------------------------------------------------------------------
// One dispatch, no barrier, no spin (R6 tail recipe), with the two measured
// pathologies fixed:
//  - R3's eps gather (36 lines PER scalar load) -> coalesced LDS staging:
//    9 perfectly-coalesced dword rounds per p-slice (18x fewer transactions),
//    double-buffered so stage(p+1) latency hides under eval(p).
//  - R6's serial {load->ballot->tree} loop -> all 8 masks ballot'd up-front,
//    acc[8] in registers across the p-loop, ONE tree per batch at the end.
// Block (pg, bc): 8 plaquettes x 32 batches; partial[pg][b] via write-through
// agent stores; ticket elects the 8th finisher to sum pg ascending -> out.
// ---------------------------------------------------------------------------
__global__ __launch_bounds__(NTHR, 2) void fused(
    const int*   __restrict__ inputs,   // [BATCH][LSZ]
    const int*   __restrict__ plq,      // [NP][S] (unused: regular geometry)
    const float* __restrict__ eps,      // [2][NP][M][S]
    float*       __restrict__ partial,  // [PG][BATCH]  (ws, 64 KB)
    float*       __restrict__ out)      // [BATCH]
{
    __shared__ float raw[2][RAWN];      // 18.4 KB staged eps (double buffer)
    __shared__ float As[32][M];         // 16 KB  pattern bits 0..4
    __shared__ float Bs[16][M];         // 8 KB   pattern bits 5..8
    __shared__ unsigned long long smask[BPB];
    __shared__ int lastflag;

    (void)plq;

    const int t  = threadIdx.x;
    const int w  = t >> 6;
    const int l  = t & 63;
    const int pg = blockIdx.x & (PG - 1);
    const int bc = blockIdx.x >> 3;
    const int pbase = pg * PGRP;
    const int b0 = bc * BPB;

    // ---- masks for this block's 32 batches, ballot'd UP-FRONT (R6 lesson) --
    {
        int vals[BPW];
#pragma unroll
        for (int i = 0; i < BPW; ++i)
            vals[i] = inputs[(size_t)(b0 + w * BPW + i) * LSZ + l];
#pragma unroll
        for (int i = 0; i < BPW; ++i) {
            const unsigned long long mk = __ballot(vals[i] != 0);
            if (l == 0) smask[w * BPW + i] = mk;
        }
    }

    // ---- prologue: stage p = pbase into raw[0], coalesced ----
    {
        const float* pb0 = eps + (size_t)pbase * MS;           // d=0 slice
        const float* pb1 = pb0 + (size_t)NP * MS;              // d=1 slice
#pragma unroll
        for (int k = 0; k < 9; ++k) {
            const int idx = k * NTHR + t;                      // 0..2303
            raw[0][idx] = (idx < MS) ? pb0[idx] : pb1[idx - MS];
        }
    }
    __syncthreads();   // masks + raw[0] ready

    const unsigned long long my64 = smask[w * BPW + (l & 7)];

    const int m    = t & 127;
    const int half = t >> 7;

    float acc[BPW];
#pragma unroll
    for (int i = 0; i < BPW; ++i) acc[i] = 0.f;

    int cur = 0;
    for (int lp = 0; lp < PGRP; ++lp) {
        // ---------------- build As/Bs for p = pbase+lp from raw[cur] --------
        {
            float e0[S], e1[S];
#pragma unroll
            for (int s = 0; s < S; ++s) {
                e0[s] = raw[cur][m * 9 + s];
                e1[s] = raw[cur][MS + m * 9 + s];
            }
            float c01[4], b56[4];
#pragma unroll
            for (int i = 0; i < 4; ++i) {
                c01[i] = ((i & 1) ? e1[0] : e0[0]) * ((i & 2) ? e1[1] : e0[1]);
                b56[i] = ((i & 1) ? e1[5] : e0[5]) * ((i & 2) ? e1[6] : e0[6]);
            }
            const float e4v = half ? e1[4] : e0[4];
            float c234[4];
#pragma unroll
            for (int j = 0; j < 4; ++j)
                c234[j] = ((j & 1) ? e1[2] : e0[2]) *
                          ((j & 2) ? e1[3] : e0[3]) * e4v;
            const int lob = half * 16;
#pragma unroll
            for (int k = 0; k < 16; ++k)
                As[lob + k][m] = c01[k & 3] * c234[k >> 2];
            const float e8v = half ? e1[8] : e0[8];
            const float b78_0 = e0[7] * e8v;
            const float b78_1 = e1[7] * e8v;
            const int hib = half * 8;
#pragma unroll
            for (int k = 0; k < 8; ++k)
                Bs[hib + k][m] = b56[k & 3] * ((k & 4) ? b78_1 : b78_0);
        }

        // ---- issue next p's stage loads (regs); land during eval ----
        float stg[9];
        const int havenext = (lp + 1 < PGRP);
        if (havenext) {
            const float* pb0 = eps + (size_t)(pbase + lp + 1) * MS;
            const float* pb1 = pb0 + (size_t)NP * MS;
#pragma unroll
            for (int k = 0; k < 9; ++k) {
                const int idx = k * NTHR + t;
                stg[k] = (idx < MS) ? pb0[idx] : pb1[idx - MS];
            }
        }
        __syncthreads();   // As/Bs ready; raw[cur] free

        // ---------------- eval p = pbase+lp for my 8 batches ----------------
        {
            const int p  = pbase + lp;
            const int pi = p >> 3;
            const int pj = p & 7;
            int pat = 0;   // pattern of batch (l&7) at plaquette p
#pragma unroll
            for (int di = 0; di < 3; ++di) {
                const int r = (pi + di) & 7;
                const unsigned row = (unsigned)(my64 >> (8 * r)) & 0xFFu;
                pat |= (int)(((row | (row << 8)) >> pj) & 7u) << (3 * di);
            }
#pragma unroll
            for (int i = 0; i < BPW; ++i) {
                const int up = __shfl(pat, i, 64);   // batch i's pattern
                const int lo = up & 31;
                const int hi = up >> 5;
                acc[i] = fmaf(As[lo][l],      Bs[hi][l],      acc[i]);
                acc[i] = fmaf(As[lo][l + 64], Bs[hi][l + 64], acc[i]);
            }
        }

        // ---- write staged regs into the other raw buffer ----
        if (havenext) {
#pragma unroll
            for (int k = 0; k < 9; ++k)
                raw[cur ^ 1][k * NTHR + t] = stg[k];
            cur ^= 1;
        }
        __syncthreads();   // raw[new cur] complete; As/Bs free for next build
    }

    // ---------------- one tree per batch, write partials ----------------
#pragma unroll
    for (int i = 0; i < BPW; ++i) {
        float v = acc[i];
#pragma unroll
        for (int off = 32; off > 0; off >>= 1)
            v += __shfl_down(v, off, 64);
        if (l == 0)
            __hip_atomic_store(&partial[(size_t)pg * BATCH + b0 + w * BPW + i],
                               v, __ATOMIC_RELAXED, __HIP_MEMORY_SCOPE_AGENT);
    }
    __syncthreads();   // barrier waitcnt drains the partial stores

    // ---------------- no-spin ticket tail (R6-proven recipe) ----------------
    if (t == 0) {
        const unsigned old =
            __hip_atomic_fetch_add(&g_tk[bc], 1u, __ATOMIC_RELAXED,
                                   __HIP_MEMORY_SCOPE_AGENT);
        lastflag = ((old & 7u) == 7u);
    }
    __syncthreads();
    if (lastflag && t < BPB) {
        float s = 0.f;
#pragma unroll
        for (int g = 0; g < PG; ++g)
            s += partial[(size_t)g * BATCH + b0 + t];  // ascending g: determin.
        out[b0 + t] = s;
    }
}

extern "C" void kernel_launch(void* const* d_in, const int* in_sizes, int n_in,
                              void* d_out, int out_size, void* d_ws, size_t ws_size,
                              hipStream_t stream) {
    const int*   inputs = (const int*)d_in[0];    // (BATCH, L) int32
    const int*   plq    = (const int*)d_in[1];    // (NP, 9) int32
    const float* eps    = (const float*)d_in[2];  // (2, NP, M, 9) fp32
    float* out = (float*)d_out;                   // (BATCH,) fp32
    float* partial = (float*)d_ws;                // PG*BATCH floats = 64 KB

    fused<<<NBLK, NTHR, 0, stream>>>(inputs, plq, eps, partial, out);
}

// Round 8
// 66.778 us; speedup vs baseline: 1.4497x; 1.0901x over previous
//
#include <hip/hip_runtime.h>
#include <stdint.h>

#define S 9          // PW*PW
#define LSZ 64       // GRID*GRID sites
#define NP 64        // plaquettes
#define M 128
#define BATCH 2048
#define MS (M * S)   // 1152 floats per (d,p) slice

#define NCH  8               // batch chunks
#define CHB  256             // batches per chunk
#define NTHR 256
#define NBLK (NP * NCH)      // 512 blocks: block = (p, chunk)
#define STRIDE (M + 4)       // 132 dwords: row base bank-group = (4*row)%32

// Monotonic per-chunk tickets in .bss (zeroed at load, never reset;
// wrap-safe: 2^32 % 64 == 0). The 64th finisher of a chunk owns the tail.
__device__ unsigned g_tk[NCH];

// ---------------------------------------------------------------------------
// One dispatch, no barrier, no spin; LDS instruction count cut ~10x vs R7
// (R7 post-mortem: 83 LDS instr/thread/iter = LDS-issue bound at ~20us).
//
// Block (p, bc):
//  1. build As[32][M]/Bs[16][M] for its single p, ONCE (direct eps gather,
//     issued first so latency hides under the mask phase).
//  2. mask phase: each wave ballots its 64 batches, 8-deep double-buffered
//     (R6 lesson: never serialize load->ballot->use per batch).
//  3. LANE-PARALLEL eval: lane i owns batch i: 64x ds_read_b128 dot of
//     As[lo_i][.]*Bs[hi_i][.] into 4 regs. No shuffle trees; result is
//     already lane-coalesced.
//  4. write-through agent store of 256 partials + barrier (vmcnt drain) +
//     relaxed ticket; 64th finisher sums p ascending -> out (R6/R7-verified
//     visibility recipe).
// ---------------------------------------------------------------------------
__global__ __launch_bounds__(NTHR, 2) void fused(
    const int*   __restrict__ inputs,   // [BATCH][LSZ]
    const int*   __restrict__ plq,      // [NP][S] (unused: regular geometry)
    const float* __restrict__ eps,      // [2][NP][M][S]
    float*       __restrict__ partial,  // [NP][BATCH]  (ws, 512 KB)
    float*       __restrict__ out)      // [BATCH]
{
    __shared__ float As[32][STRIDE];            // 16.9 KB
    __shared__ float Bs[16][STRIDE];            // 8.4 KB
    __shared__ unsigned long long smask[CHB];   // 2 KB
    __shared__ int lastflag;

    (void)plq;

    const int t  = threadIdx.x;
    const int w  = t >> 6;
    const int l  = t & 63;
    const int p  = blockIdx.x >> 3;     // 0..63
    const int bc = blockIdx.x & 7;      // 0..7
    const int b0 = bc * CHB;

    // ---- 1. issue eps loads FIRST (latency hides under the mask phase) ----
    const int m    = t & 127;
    const int half = t >> 7;            // As: bit4 split; Bs: bit8 split
    const float* ep = eps + (size_t)p * MS + (size_t)m * S;
    float e0[S], e1[S];
#pragma unroll
    for (int s = 0; s < S; ++s) {
        e0[s] = ep[s];
        e1[s] = ep[(size_t)NP * MS + s];
    }

    // ---- 2. mask phase: wave w ballots its 64 batches, 8-deep pipeline ----
    {
        const size_t base = (size_t)(b0 + w * 64) * LSZ + l;
        int va[8], vb[8];
#pragma unroll
        for (int j = 0; j < 8; ++j)
            va[j] = inputs[base + (size_t)j * LSZ];
        for (int c = 0; c < 8; ++c) {
            if (c < 7) {
#pragma unroll
                for (int j = 0; j < 8; ++j)
                    vb[j] = inputs[base + (size_t)((c + 1) * 8 + j) * LSZ];
            }
#pragma unroll
            for (int j = 0; j < 8; ++j) {
                const unsigned long long mk = __ballot(va[j] != 0);
                if (l == 0) smask[w * 64 + c * 8 + j] = mk;
            }
            if (c < 7) {
#pragma unroll
                for (int j = 0; j < 8; ++j) va[j] = vb[j];
            }
        }
    }

    // ---- 1b. build As/Bs (R6-verified bit-split products) ----
    {
        float c01[4], b56[4];
#pragma unroll
        for (int i = 0; i < 4; ++i) {
            c01[i] = ((i & 1) ? e1[0] : e0[0]) * ((i & 2) ? e1[1] : e0[1]);
            b56[i] = ((i & 1) ? e1[5] : e0[5]) * ((i & 2) ? e1[6] : e0[6]);
        }
        const float e4v = half ? e1[4] : e0[4];
        float c234[4];
#pragma unroll
        for (int j = 0; j < 4; ++j)
            c234[j] = ((j & 1) ? e1[2] : e0[2]) *
                      ((j & 2) ? e1[3] : e0[3]) * e4v;
        const int lob = half * 16;
#pragma unroll
        for (int k = 0; k < 16; ++k)
            As[lob + k][m] = c01[k & 3] * c234[k >> 2];
        const float e8v = half ? e1[8] : e0[8];
        const float b78_0 = e0[7] * e8v;
        const float b78_1 = e1[7] * e8v;
        const int hib = half * 8;
#pragma unroll
        for (int k = 0; k < 8; ++k)
            Bs[hib + k][m] = b56[k & 3] * ((k & 4) ? b78_1 : b78_0);
    }
    __syncthreads();   // As/Bs + smask ready

    // ---- 3. lane-parallel eval: lane i owns batch (w*64 + i) ----
    const unsigned long long my = smask[w * 64 + l];
    const int pi = p >> 3;
    const int pj = p & 7;
    int pat = 0;
#pragma unroll
    for (int di = 0; di < 3; ++di) {
        const int r = (pi + di) & 7;
        const unsigned row = (unsigned)(my >> (8 * r)) & 0xFFu;
        pat |= (int)(((row | (row << 8)) >> pj) & 7u) << (3 * di);
    }
    const float4* Ar = (const float4*)&As[pat & 31][0];   // 528B rows: aligned
    const float4* Br = (const float4*)&Bs[pat >> 5][0];
    float a0 = 0.f, a1 = 0.f, a2 = 0.f, a3 = 0.f;
#pragma unroll
    for (int k = 0; k < M / 4; ++k) {
        const float4 a = Ar[k];
        const float4 b = Br[k];
        a0 = fmaf(a.x, b.x, a0);
        a1 = fmaf(a.y, b.y, a1);
        a2 = fmaf(a.z, b.z, a2);
        a3 = fmaf(a.w, b.w, a3);
    }
    const float r = (a0 + a1) + (a2 + a3);

    // ---- 4. write-through partial store + no-spin ticket (R6/R7 recipe) ----
    __hip_atomic_store(&partial[(size_t)p * BATCH + b0 + w * 64 + l], r,
                       __ATOMIC_RELAXED, __HIP_MEMORY_SCOPE_AGENT);
    __syncthreads();   // barrier waitcnt drains the partial stores

    if (t == 0) {
        const unsigned old =
            __hip_atomic_fetch_add(&g_tk[bc], 1u, __ATOMIC_RELAXED,
                                   __HIP_MEMORY_SCOPE_AGENT);
        lastflag = ((old & 63u) == 63u);
    }
    __syncthreads();
    if (!lastflag) return;    // everyone but the 64th exits: no spin

    // ---- tail: thread t = batch b0+t, sum over p ascending (determin.) ----
    const float* pr = partial + b0 + t;
    float s = 0.f;
#pragma unroll
    for (int pp = 0; pp < NP; pp += 8) {
        const float v0 = pr[(size_t)(pp + 0) * BATCH];
        const float v1 = pr[(size_t)(pp + 1) * BATCH];
        const float v2 = pr[(size_t)(pp + 2) * BATCH];
        const float v3 = pr[(size_t)(pp + 3) * BATCH];
        const float v4 = pr[(size_t)(pp + 4) * BATCH];
        const float v5 = pr[(size_t)(pp + 5) * BATCH];
        const float v6 = pr[(size_t)(pp + 6) * BATCH];
        const float v7 = pr[(size_t)(pp + 7) * BATCH];
        s += v0; s += v1; s += v2; s += v3;
        s += v4; s += v5; s += v6; s += v7;
    }
    out[b0 + t] = s;
}

extern "C" void kernel_launch(void* const* d_in, const int* in_sizes, int n_in,
                              void* d_out, int out_size, void* d_ws, size_t ws_size,
                              hipStream_t stream) {
    const int*   inputs = (const int*)d_in[0];    // (BATCH, L) int32
    const int*   plq    = (const int*)d_in[1];    // (NP, 9) int32
    const float* eps    = (const float*)d_in[2];  // (2, NP, M, 9) fp32
    float* out = (float*)d_out;                   // (BATCH,) fp32
    float* partial = (float*)d_ws;                // NP*BATCH floats = 512 KB

    fused<<<NBLK, NTHR, 0, stream>>>(inputs, plq, eps, partial, out);
}